// Round 13
// baseline (150.673 us; speedup 1.0000x reference)
//
#include <hip/hip_runtime.h>
#include <hip/hip_bf16.h>
#include <hip/hip_fp16.h>
#include <math.h>

#ifndef M_PI
#define M_PI 3.14159265358979323846
#endif

// Problem constants
#define NN 10000      // nodes
#define NE 160000     // edges
#define NC 16         // channels
#define NQ 5          // 2*order+1
#define NFR 10        // N_FREQ * N_RINGS
#define CQ 80         // NC*NQ
#define OP 80         // outputs per node

// Fixed-bucket edge store: node n owns slots [n*MAXDEG, n*MAXDEG+deg).
// deg ~ Binomial(160000,1e-4): mean 16, sd 4; 64 = 12 sd -> safe for any seed.
#define MAXDEG 64

// Extended GEMM: k in [0,800) edge part (k = cq*10 + fr); k in [800,880)
// self part (k = 800 + cq); k in [880,896) zero pad (A and B both zero).
#define KTOT2 896
#define KS 28         // 896 / 32 MFMA k-steps
#define WTN 71680     // KTOT2 * 80 weight elements per layer
#define APAD 936      // LDS row stride fp16 (20 mod 32 banks, v12-proven)
#define NPB 4         // nodes per block (v23: 2 waves per node, 8 waves, 512 thr)
#define PPAD 21       // partial-buffer lane stride (21 mod 32 -> conflict-free)

typedef __attribute__((ext_vector_type(8))) _Float16 f16x8;
typedef __attribute__((ext_vector_type(4))) float f32x4;

static __device__ __forceinline__ unsigned short f2h_u(float f) {
    return __builtin_bit_cast(unsigned short, (_Float16)f);
}
static __device__ __forceinline__ unsigned pack2h(float lo, float hi) {
    return (unsigned)f2h_u(lo) | ((unsigned)f2h_u(hi) << 16);
}
#define RFL(x) __builtin_amdgcn_readfirstlane(x)

// ---------------------------------------------------------------------------
// prep_all: ONE dispatch does everything the layers need.
//  i < NE:  edge i claims rank = atomicAdd(cnt[dst]) and writes its record
//           {tv[0..9], c1, s1} (48 B) + src id into node dst's fixed bucket.
//  i < WTN: reorder W+Ws into MFMA-B fragment order (k-map above, R10-proven).
// ---------------------------------------------------------------------------
__global__ void prep_all(const int* __restrict__ ei, const float* __restrict__ phi,
                         const float* __restrict__ pre,
                         const float* __restrict__ W1, const float* __restrict__ Ws1,
                         const float* __restrict__ W2, const float* __restrict__ Ws2,
                         int* __restrict__ cnt, int* __restrict__ srcs,
                         float4* __restrict__ recs,
                         unsigned short* __restrict__ Wt1, unsigned short* __restrict__ Wt2) {
    int i = blockIdx.x * blockDim.x + threadIdx.x;
    if (i < NE) {
        const int dst  = ei[2 * i + 1];
        const int srcn = ei[2 * i];
        const int rank = atomicAdd(&cnt[dst], 1);
        if (rank < MAXDEG) {               // can't overflow for this dataset; guard vs OOB
            float s1, c1;
            sincosf(phi[i], &s1, &c1);
            const float* tp = pre + (size_t)i * NFR;
            const int slot = dst * MAXDEG + rank;
            float4* rp = recs + (size_t)slot * 3;
            rp[0] = make_float4(tp[0], tp[1], tp[2], tp[3]);
            rp[1] = make_float4(tp[4], tp[5], tp[6], tp[7]);
            rp[2] = make_float4(tp[8], tp[9], c1, s1);
            srcs[slot] = srcn;
        }
    }
    if (i < WTN) {
        int j    = i & 7;
        int lane = (i >> 3) & 63;
        int grp  = i >> 9;            // 0..139 = ks*5 + nt
        int ks   = grp / 5;
        int nt   = grp % 5;
        int quad = lane >> 4;
        int lrow = lane & 15;
        int n    = 16 * nt + lrow;    // output index op
        int k    = 32 * ks + 8 * quad + j;
        int o = n / 5, p = n % 5;
        float v1, v2;
        if (k < 800) {                // edge part: k = cq*10 + fr
            int cq = k / 10, fr = k % 10;
            int c = cq / 5, q = cq % 5;
            int f = fr >> 1, r = fr & 1;
            int src = ((((o * NC + c) * NQ + p) * NQ + q) * 5 + f) * 2 + r;
            v1 = W1[src]; v2 = W2[src];
        } else if (k < 880) {         // self part: k = 800 + cq
            int cq = k - 800;
            int c = cq / 5, q = cq % 5;
            int src = ((o * NC + c) * NQ + p) * NQ + q;
            v1 = Ws1[src]; v2 = Ws2[src];
        } else {                      // pad
            v1 = 0.0f; v2 = 0.0f;
        }
        Wt1[i] = f2h_u(v1); Wt2[i] = f2h_u(v2);
    }
}

// ---------------------------------------------------------------------------
// layer_fused v23: TWO WAVES PER NODE (4 nodes / 8 waves / 512 threads).
//
// R12 budget analysis: fixed harness cost ~80-85 us; layers ~22 us each vs a
// ~6 us issue model. Gap = per-wave serial depth (16 edges) x block-barrier
// straggler (max of 8 node degrees) + prologue amortization. v23 halves both:
// even wave of a node-pair aggregates edges [0, ceil(deg/2)), odd wave the
// rest, each with the v22 depth-2 pipeline; odd wave's 20 fp32 partials/lane
// go through LDS (stride-21, conflict-free) and the even wave adds + packs.
// fp32 add-reorder only (accumulation reorders passed in v13/v14).
// GEMM unchanged on a 4-row A tile (arow = lrow&3, D rows 0-3 stored).
// ---------------------------------------------------------------------------
__global__ __launch_bounds__(512)
void layer_fused(const float* __restrict__ xin, const int* __restrict__ srcs,
                 const float4* __restrict__ recs, const int* __restrict__ cnt,
                 const unsigned short* __restrict__ Wt, const float* __restrict__ b,
                 const float* __restrict__ res,   // residual (x) or nullptr
                 float* __restrict__ outp) {
    __shared__ __align__(16) unsigned short A_s[NPB * APAD];  //  7,488 B
    __shared__ float part_s[NPB][64][PPAD];                   // 21,504 B
    __shared__ float y_s[NPB * OP];                           //  1,280 B

    const int tid = threadIdx.x;
    const int n0 = blockIdx.x * NPB;             // NN = 2500*4 exactly
    const int wid = RFL(tid >> 6);               // wave id (SGPR)
    const int lane = tid & 63;
    const int nl   = wid >> 1;                   // local node 0..3
    const int half = wid & 1;                    // edge-range half
    const int n = n0 + nl;

    // ---- lane roles (lanes 48..63 clamped to in-bounds dummy work) ----
    const int l48 = (lane < 48) ? lane : 0;
    const int c   = l48 / 3;
    const int g   = l48 - 3 * c;                 // 0,1,2
    const int cqA = 5 * c + ((g == 0) ? 0 : (g == 1) ? 1 : 3);
    const int cqB = cqA + 1;                     // partner (ignored for g==0)
    const bool hi = (g == 2);

    const int base = n * MAXDEG;
    int deg = RFL(cnt[n]);
    if (deg > MAXDEG) deg = MAXDEG;

    // this wave's edge range: even wave [0,h), odd wave [h,deg)
    const int h   = (deg + 1) >> 1;
    const int loE = half ? h : 0;
    const int cntE = (half ? deg : h) - loE;

    // prefetch self-interaction x values (used in pack phase, even wave)
    const float xselfA = xin[(size_t)n * CQ + cqA];
    const float xselfB = xin[(size_t)n * CQ + cqB];

    float accA[10], accB[10];
    #pragma unroll
    for (int f = 0; f < 10; ++f) { accA[f] = 0.f; accB[f] = 0.f; }

    // EDGE: record floats are SGPR (uniform); xa/xb per-lane VGPR loads.
#define EDGE_FMA(r0, r1, r2, xa, xb)                                          \
    do {                                                                      \
        const float c1 = (r2).z, s1 = (r2).w;                                 \
        const float c2 = c1 * c1 - s1 * s1;                                   \
        const float s2 = 2.0f * c1 * s1;                                      \
        const float cs = hi ? c2 : c1;                                        \
        const float sn = hi ? s2 : s1;                                        \
        const float xtA = (g == 0) ? (xa) : (cs * (xa) - sn * (xb));          \
        const float xtB = sn * (xa) + cs * (xb);                              \
        accA[0] += xtA * (r0).x;  accB[0] += xtB * (r0).x;                    \
        accA[1] += xtA * (r0).y;  accB[1] += xtB * (r0).y;                    \
        accA[2] += xtA * (r0).z;  accB[2] += xtB * (r0).z;                    \
        accA[3] += xtA * (r0).w;  accB[3] += xtB * (r0).w;                    \
        accA[4] += xtA * (r1).x;  accB[4] += xtB * (r1).x;                    \
        accA[5] += xtA * (r1).y;  accB[5] += xtB * (r1).y;                    \
        accA[6] += xtA * (r1).z;  accB[6] += xtB * (r1).z;                    \
        accA[7] += xtA * (r1).w;  accB[7] += xtB * (r1).w;                    \
        accA[8] += xtA * (r2).x;  accB[8] += xtB * (r2).x;                    \
        accA[9] += xtA * (r2).y;  accB[9] += xtB * (r2).y;                    \
    } while (0)

    if (cntE > 0) {
        // slot(i): clamped range index (prefetch-safe, always in-bounds)
        #define SLOT(i) (base + loE + (((i) < cntE) ? (i) : (cntE - 1)))
        // ---- depth-2 prologue: windows 0 (slots 0,1) and 1 (slots 2,3) ----
        int sA0 = RFL(srcs[SLOT(0)]);
        int sB0 = RFL(srcs[SLOT(1)]);
        int sA1 = RFL(srcs[SLOT(2)]);
        int sB1 = RFL(srcs[SLOT(3)]);
        const float4* p;
        p = recs + (size_t)SLOT(0) * 3; float4 rA0a = p[0], rA0b = p[1], rA0c = p[2];
        p = recs + (size_t)SLOT(1) * 3; float4 rB0a = p[0], rB0b = p[1], rB0c = p[2];
        p = recs + (size_t)SLOT(2) * 3; float4 rA1a = p[0], rA1b = p[1], rA1c = p[2];
        p = recs + (size_t)SLOT(3) * 3; float4 rB1a = p[0], rB1b = p[1], rB1c = p[2];
        const float* xr;
        xr = xin + (size_t)sA0 * CQ; float xaA = xr[cqA], xbA = xr[cqB];
        xr = xin + (size_t)sB0 * CQ; float xaB = xr[cqA], xbB = xr[cqB];

        int i = 0;
        for (; i + 2 <= cntE; i += 2) {
            // prefetch srcs window w+2
            const int nsA = RFL(srcs[SLOT(i + 4)]);
            const int nsB = RFL(srcs[SLOT(i + 5)]);
            // prefetch x window w+1 (addresses ready: sA1/sB1)
            const float* x1 = xin + (size_t)sA1 * CQ;
            const float* x2 = xin + (size_t)sB1 * CQ;
            const float nxaA = x1[cqA], nxbA = x1[cqB];
            const float nxaB = x2[cqA], nxbB = x2[cqB];
            // prefetch recs window w+2
            const float4* q1 = recs + (size_t)SLOT(i + 4) * 3;
            const float4* q2 = recs + (size_t)SLOT(i + 5) * 3;
            const float4 nrAa = q1[0], nrAb = q1[1], nrAc = q1[2];
            const float4 nrBa = q2[0], nrBb = q2[1], nrBc = q2[2];
            // compute window w (slot order preserved within each half)
            EDGE_FMA(rA0a, rA0b, rA0c, xaA, xbA);
            EDGE_FMA(rB0a, rB0b, rB0c, xaB, xbB);
            // rotate pipeline state
            sA0 = sA1; sB0 = sB1; sA1 = nsA; sB1 = nsB;
            xaA = nxaA; xbA = nxbA; xaB = nxaB; xbB = nxbB;
            rA0a = rA1a; rA0b = rA1b; rA0c = rA1c;
            rB0a = rB1a; rB0b = rB1b; rB0c = rB1c;
            rA1a = nrAa; rA1b = nrAb; rA1c = nrAc;
            rB1a = nrBa; rB1b = nrBb; rB1c = nrBc;
        }
        if (cntE & 1) {  // tail edge cntE-1: window-0 state holds slot(cntE-1)
            EDGE_FMA(rA0a, rA0b, rA0c, xaA, xbA);
        }
        #undef SLOT
    }
#undef EDGE_FMA

    // ---- combine halves: odd wave -> LDS partials; even wave adds + packs ----
    if (half == 1) {
        float* pp = &part_s[nl][lane][0];
        #pragma unroll
        for (int j = 0; j < 10; ++j) { pp[j] = accA[j]; pp[10 + j] = accB[j]; }
    }
    __syncthreads();

    if (half == 0) {
        const float* pp = &part_s[nl][lane][0];
        #pragma unroll
        for (int j = 0; j < 10; ++j) { accA[j] += pp[j]; accB[j] += pp[10 + j]; }

        // A-row write (k = cq*10 + fr), self column, zero pad
        if (lane < 48) {
            unsigned* awA = (unsigned*)&A_s[nl * APAD + cqA * 10];
            awA[0] = pack2h(accA[0], accA[1]);
            awA[1] = pack2h(accA[2], accA[3]);
            awA[2] = pack2h(accA[4], accA[5]);
            awA[3] = pack2h(accA[6], accA[7]);
            awA[4] = pack2h(accA[8], accA[9]);
            A_s[nl * APAD + 800 + cqA] = f2h_u(xselfA);
            if (g != 0) {
                unsigned* awB = (unsigned*)&A_s[nl * APAD + cqB * 10];
                awB[0] = pack2h(accB[0], accB[1]);
                awB[1] = pack2h(accB[2], accB[3]);
                awB[2] = pack2h(accB[4], accB[5]);
                awB[3] = pack2h(accB[6], accB[7]);
                awB[4] = pack2h(accB[8], accB[9]);
                A_s[nl * APAD + 800 + cqB] = f2h_u(xselfB);
            }
        }
        if (lane < 16) A_s[nl * APAD + 880 + lane] = 0;
    }
    __syncthreads();

    // ---- GEMM: y[4 x 80] = A_s[4 x 896] @ B'[896 x 80] (waves 0-4) ----
    // A row = lrow&3 (rows 4-15 duplicate rows 0-3; D rows 4-15 discarded).
    if (tid < 320) {
        const int nt = tid >> 6, lq = tid & 63;
        const int lrow = lq & 15, quad = lq >> 4;
        const int arow = lrow & 3;
        const f16x8* __restrict__ wf = (const f16x8*)Wt;
        f32x4 acc = (f32x4){0.f, 0.f, 0.f, 0.f};
        #pragma unroll 4
        for (int ks = 0; ks < KS; ++ks) {
            f16x8 bfrag = wf[(ks * 5 + nt) * 64 + lq];
            f16x8 a = *(const f16x8*)(&A_s[arow * APAD + 32 * ks + 8 * quad]);
            acc = __builtin_amdgcn_mfma_f32_16x16x32_f16(a, bfrag, acc, 0, 0, 0);
        }
        const int op = 16 * nt + lrow;
        const float bias = (op % 5 == 0) ? b[op / 5] : 0.0f;
        if (quad == 0) {                         // D rows 0..3 only
            #pragma unroll
            for (int r = 0; r < 4; ++r)
                y_s[r * OP + op] = acc[r] + bias;
        }
    }
    __syncthreads();

    // ---- epilogue: 64 threads, one (node, channel) each ----
    if (tid < 64) {
        const int nle = tid >> 4;                // node 0..3
        const int ch  = tid & 15;                // channel
        const float* vp = &y_s[nle * OP + ch * 5];
        float a0 = vp[0], a1 = vp[1], a2 = vp[2], a3 = vp[3], a4 = vp[4];
        if (res != nullptr) {
            const float* rp = res + (size_t)(n0 + nle) * CQ + ch * 5;
            a0 += rp[0]; a1 += rp[1]; a2 += rp[2]; a3 += rp[3]; a4 += rp[4];
        }
        float o0 = 0.f, o1 = 0.f, o2 = 0.f, o3 = 0.f, o4 = 0.f;
        #pragma unroll
        for (int k = 0; k < 7; ++k) {
            float th = (float)(2.0 * M_PI / 7.0) * (float)k;
            float c1k = cosf(th), s1k = sinf(th);
            float c2k = cosf(2.0f * th), s2k = sinf(2.0f * th);
            float s = a0 + a1 * c1k + a2 * s1k + a3 * c2k + a4 * s2k;
            s = fmaxf(s, 0.0f);
            o0 += s;
            o1 += s * c1k; o2 += s * s1k;
            o3 += s * c2k; o4 += s * s2k;
        }
        const float i7 = 1.0f / 7.0f, t7 = 2.0f / 7.0f;
        float* po = outp + (size_t)(n0 + nle) * OP + ch * 5;
        po[0] = o0 * i7;
        po[1] = o1 * t7; po[2] = o2 * t7;
        po[3] = o3 * t7; po[4] = o4 * t7;
    }
}

// ---------------------------------------------------------------------------
extern "C" void kernel_launch(void* const* d_in, const int* in_sizes, int n_in,
                              void* d_out, int out_size, void* d_ws, size_t ws_size,
                              hipStream_t stream) {
    const float* x    = (const float*)d_in[0];
    const int*   ei   = (const int*)d_in[1];      // int inputs arrive as int32
    const float* pre  = (const float*)d_in[2];
    const float* phi  = (const float*)d_in[3];
    const float* W1   = (const float*)d_in[4];
    const float* b1   = (const float*)d_in[5];
    const float* Ws1  = (const float*)d_in[6];
    const float* W2   = (const float*)d_in[7];
    const float* b2   = (const float*)d_in[8];
    const float* Ws2  = (const float*)d_in[9];
    float* out = (float*)d_out;

    // Workspace layout (~37 MB of the 256 MB ws)
    unsigned short* Wt1 = (unsigned short*)d_ws;            // 143.4 KB
    unsigned short* Wt2 = Wt1 + WTN;                        // 143.4 KB
    float* h  = (float*)(Wt2 + WTN);                        // 3.2 MB
    float4* recs = (float4*)(h + (size_t)NN * OP);          // 30.72 MB (16B aligned)
    int* srcs   = (int*)(recs + (size_t)NN * MAXDEG * 3);   // 2.56 MB
    int* cnt    = srcs + (size_t)NN * MAXDEG;               // 40 KB

    // 4-dispatch chain: memset -> prep_all -> layer1 -> layer2
    hipMemsetAsync(cnt, 0, NN * sizeof(int), stream);
    prep_all<<<(NE + 255) / 256, 256, 0, stream>>>(ei, phi, pre, W1, Ws1, W2, Ws2,
                                                   cnt, srcs, recs, Wt1, Wt2);
    layer_fused<<<NN / NPB, 512, 0, stream>>>(x, srcs, recs, cnt, Wt1, b1, nullptr, h);
    layer_fused<<<NN / NPB, 512, 0, stream>>>(h, srcs, recs, cnt, Wt2, b2, x, out);
}

// Round 14
// 148.384 us; speedup vs baseline: 1.0154x; 1.0154x over previous
//
#include <hip/hip_runtime.h>
#include <hip/hip_bf16.h>
#include <hip/hip_fp16.h>
#include <math.h>

#ifndef M_PI
#define M_PI 3.14159265358979323846
#endif

// Problem constants
#define NN 10000      // nodes
#define NE 160000     // edges
#define NC 16         // channels
#define NQ 5          // 2*order+1
#define NFR 10        // N_FREQ * N_RINGS
#define CQ 80         // NC*NQ
#define OP 80         // outputs per node

// Fixed-bucket edge store: node n owns slots [n*MAXDEG, n*MAXDEG+deg).
// deg ~ Binomial(160000,1e-4): mean 16, sd 4; 64 = 12 sd -> safe for any seed.
#define MAXDEG 64

// Extended GEMM: k in [0,800) edge part (k = cq*10 + fr); k in [800,880)
// self part (k = 800 + cq); k in [880,896) zero pad (A and B both zero).
#define KTOT2 896
#define KS 28         // 896 / 32 MFMA k-steps
#define WTN 71680     // KTOT2 * 80 weight elements per layer
#define APAD 936      // LDS row stride fp16 (20 mod 32 banks, v12-proven)
#define NPB 8         // nodes per block (8 waves, 512 threads)

typedef __attribute__((ext_vector_type(8))) _Float16 f16x8;
typedef __attribute__((ext_vector_type(4))) float f32x4;

static __device__ __forceinline__ unsigned short f2h_u(float f) {
    return __builtin_bit_cast(unsigned short, (_Float16)f);
}
static __device__ __forceinline__ unsigned pack2h(float lo, float hi) {
    return (unsigned)f2h_u(lo) | ((unsigned)f2h_u(hi) << 16);
}
#define RFL(x) __builtin_amdgcn_readfirstlane(x)

// ---------------------------------------------------------------------------
// prep_all: ONE dispatch does everything the layers need.
//  i < NE:  edge i claims rank = atomicAdd(cnt[dst]) and writes its record
//           {tv[0..9], c1, s1} (48 B) + src id into node dst's fixed bucket.
//  i < WTN: reorder W+Ws into MFMA-B fragment order (k-map above, R10-proven).
// ---------------------------------------------------------------------------
__global__ void prep_all(const int* __restrict__ ei, const float* __restrict__ phi,
                         const float* __restrict__ pre,
                         const float* __restrict__ W1, const float* __restrict__ Ws1,
                         const float* __restrict__ W2, const float* __restrict__ Ws2,
                         int* __restrict__ cnt, int* __restrict__ srcs,
                         float4* __restrict__ recs,
                         unsigned short* __restrict__ Wt1, unsigned short* __restrict__ Wt2) {
    int i = blockIdx.x * blockDim.x + threadIdx.x;
    if (i < NE) {
        const int dst  = ei[2 * i + 1];
        const int srcn = ei[2 * i];
        const int rank = atomicAdd(&cnt[dst], 1);
        if (rank < MAXDEG) {               // can't overflow for this dataset; guard vs OOB
            float s1, c1;
            sincosf(phi[i], &s1, &c1);
            const float* tp = pre + (size_t)i * NFR;
            const int slot = dst * MAXDEG + rank;
            float4* rp = recs + (size_t)slot * 3;
            rp[0] = make_float4(tp[0], tp[1], tp[2], tp[3]);
            rp[1] = make_float4(tp[4], tp[5], tp[6], tp[7]);
            rp[2] = make_float4(tp[8], tp[9], c1, s1);
            srcs[slot] = srcn;
        }
    }
    if (i < WTN) {
        int j    = i & 7;
        int lane = (i >> 3) & 63;
        int grp  = i >> 9;            // 0..139 = ks*5 + nt
        int ks   = grp / 5;
        int nt   = grp % 5;
        int quad = lane >> 4;
        int lrow = lane & 15;
        int n    = 16 * nt + lrow;    // output index op
        int k    = 32 * ks + 8 * quad + j;
        int o = n / 5, p = n % 5;
        float v1, v2;
        if (k < 800) {                // edge part: k = cq*10 + fr
            int cq = k / 10, fr = k % 10;
            int c = cq / 5, q = cq % 5;
            int f = fr >> 1, r = fr & 1;
            int src = ((((o * NC + c) * NQ + p) * NQ + q) * 5 + f) * 2 + r;
            v1 = W1[src]; v2 = W2[src];
        } else if (k < 880) {         // self part: k = 800 + cq
            int cq = k - 800;
            int c = cq / 5, q = cq % 5;
            int src = ((o * NC + c) * NQ + p) * NQ + q;
            v1 = Ws1[src]; v2 = Ws2[src];
        } else {                      // pad
            v1 = 0.0f; v2 = 0.0f;
        }
        Wt1[i] = f2h_u(v1); Wt2[i] = f2h_u(v2);
    }
}

// ---------------------------------------------------------------------------
// layer_fused v24 = verified v22 (8 nodes / 512 threads, 1 wave/node, SGPR
// records, 4 blocks/CU) with the x-gather pipeline deepened to DEPTH-2:
// three srcs windows held (sA0..sB2); per iteration issue srcs w+3, x w+2
// (addresses ready from last iteration's srcs), recs w+2; compute window w.
// x-load coverage doubles (~2 loop bodies ~ L2 latency). FMA slot order
// unchanged -> bit-identical values to v22. (v23's 2-wave split regressed:
// doubled prologue amortization cost; reverted.)
// ---------------------------------------------------------------------------
__global__ __launch_bounds__(512)
void layer_fused(const float* __restrict__ xin, const int* __restrict__ srcs,
                 const float4* __restrict__ recs, const int* __restrict__ cnt,
                 const unsigned short* __restrict__ Wt, const float* __restrict__ b,
                 const float* __restrict__ res,   // residual (x) or nullptr
                 float* __restrict__ outp) {
    __shared__ __align__(16) unsigned short A_s[NPB * APAD];  // 14,976 B
    __shared__ float y_s[NPB * OP];                           //  2,560 B

    const int tid = threadIdx.x;
    const int n0 = blockIdx.x * NPB;             // NN = 1250*8 exactly
    const int wid = RFL(tid >> 6);               // wave id = local node (SGPR)
    const int lane = tid & 63;
    const int n = n0 + wid;

    // ---- lane roles (lanes 48..63 clamped to in-bounds dummy work) ----
    const int l48 = (lane < 48) ? lane : 0;
    const int c   = l48 / 3;
    const int g   = l48 - 3 * c;                 // 0,1,2
    const int cqA = 5 * c + ((g == 0) ? 0 : (g == 1) ? 1 : 3);
    const int cqB = cqA + 1;                     // partner (ignored for g==0)
    const bool hi = (g == 2);

    const int base = n * MAXDEG;
    int deg = RFL(cnt[n]);
    if (deg > MAXDEG) deg = MAXDEG;

    float accA[10], accB[10];
    #pragma unroll
    for (int f = 0; f < 10; ++f) { accA[f] = 0.f; accB[f] = 0.f; }

    // EDGE: record floats are SGPR (uniform); xa/xb per-lane VGPR loads.
#define EDGE_FMA(r0, r1, r2, xa, xb)                                          \
    do {                                                                      \
        const float c1 = (r2).z, s1 = (r2).w;                                 \
        const float c2 = c1 * c1 - s1 * s1;                                   \
        const float s2 = 2.0f * c1 * s1;                                      \
        const float cs = hi ? c2 : c1;                                        \
        const float sn = hi ? s2 : s1;                                        \
        const float xtA = (g == 0) ? (xa) : (cs * (xa) - sn * (xb));          \
        const float xtB = sn * (xa) + cs * (xb);                              \
        accA[0] += xtA * (r0).x;  accB[0] += xtB * (r0).x;                    \
        accA[1] += xtA * (r0).y;  accB[1] += xtB * (r0).y;                    \
        accA[2] += xtA * (r0).z;  accB[2] += xtB * (r0).z;                    \
        accA[3] += xtA * (r0).w;  accB[3] += xtB * (r0).w;                    \
        accA[4] += xtA * (r1).x;  accB[4] += xtB * (r1).x;                    \
        accA[5] += xtA * (r1).y;  accB[5] += xtB * (r1).y;                    \
        accA[6] += xtA * (r1).z;  accB[6] += xtB * (r1).z;                    \
        accA[7] += xtA * (r1).w;  accB[7] += xtB * (r1).w;                    \
        accA[8] += xtA * (r2).x;  accB[8] += xtB * (r2).x;                    \
        accA[9] += xtA * (r2).y;  accB[9] += xtB * (r2).y;                    \
    } while (0)

    if (deg > 0) {
        // slot(i): clamped bucket index (prefetch-safe, always in-bounds)
        #define SLOT(i) (base + (((i) < deg) ? (i) : (deg - 1)))
        // ---- prologue: srcs windows 0,1,2; recs windows 0,1; x windows 0,1
        int sA0 = RFL(srcs[SLOT(0)]);
        int sB0 = RFL(srcs[SLOT(1)]);
        int sA1 = RFL(srcs[SLOT(2)]);
        int sB1 = RFL(srcs[SLOT(3)]);
        int sA2 = RFL(srcs[SLOT(4)]);
        int sB2 = RFL(srcs[SLOT(5)]);
        const float4* p;
        p = recs + (size_t)SLOT(0) * 3; float4 rA0a = p[0], rA0b = p[1], rA0c = p[2];
        p = recs + (size_t)SLOT(1) * 3; float4 rB0a = p[0], rB0b = p[1], rB0c = p[2];
        p = recs + (size_t)SLOT(2) * 3; float4 rA1a = p[0], rA1b = p[1], rA1c = p[2];
        p = recs + (size_t)SLOT(3) * 3; float4 rB1a = p[0], rB1b = p[1], rB1c = p[2];
        const float* xr;
        xr = xin + (size_t)sA0 * CQ; float xaA0 = xr[cqA], xbA0 = xr[cqB];
        xr = xin + (size_t)sB0 * CQ; float xaB0 = xr[cqA], xbB0 = xr[cqB];
        xr = xin + (size_t)sA1 * CQ; float xaA1 = xr[cqA], xbA1 = xr[cqB];
        xr = xin + (size_t)sB1 * CQ; float xaB1 = xr[cqA], xbB1 = xr[cqB];

        int i = 0;
        for (; i + 2 <= deg; i += 2) {
            // prefetch srcs window w+3
            const int nsA = RFL(srcs[SLOT(i + 6)]);
            const int nsB = RFL(srcs[SLOT(i + 7)]);
            // prefetch x window w+2 (addresses ready: sA2/sB2, loaded 2 back)
            const float* x1 = xin + (size_t)sA2 * CQ;
            const float* x2 = xin + (size_t)sB2 * CQ;
            const float nxaA = x1[cqA], nxbA = x1[cqB];
            const float nxaB = x2[cqA], nxbB = x2[cqB];
            // prefetch recs window w+2
            const float4* q1 = recs + (size_t)SLOT(i + 4) * 3;
            const float4* q2 = recs + (size_t)SLOT(i + 5) * 3;
            const float4 nrAa = q1[0], nrAb = q1[1], nrAc = q1[2];
            const float4 nrBa = q2[0], nrBb = q2[1], nrBc = q2[2];
            // compute window w (slot order preserved -> v22-identical values)
            EDGE_FMA(rA0a, rA0b, rA0c, xaA0, xbA0);
            EDGE_FMA(rB0a, rB0b, rB0c, xaB0, xbB0);
            // rotate pipeline state
            sA0 = sA1; sB0 = sB1; sA1 = sA2; sB1 = sB2; sA2 = nsA; sB2 = nsB;
            xaA0 = xaA1; xbA0 = xbA1; xaB0 = xaB1; xbB0 = xbB1;
            xaA1 = nxaA; xbA1 = nxbA; xaB1 = nxaB; xbB1 = nxbB;
            rA0a = rA1a; rA0b = rA1b; rA0c = rA1c;
            rB0a = rB1a; rB0b = rB1b; rB0c = rB1c;
            rA1a = nrAa; rA1b = nrAb; rA1c = nrAc;
            rB1a = nrBa; rB1b = nrBb; rB1c = nrBc;
        }
        if (deg & 1) {   // tail edge deg-1: window-0 state holds slot(deg-1)
            EDGE_FMA(rA0a, rA0b, rA0c, xaA0, xbA0);
        }
        #undef SLOT
    }
#undef EDGE_FMA

    // ---- A-row write (k = cq*10 + fr), self column, zero pad ----
    if (lane < 48) {
        unsigned* awA = (unsigned*)&A_s[wid * APAD + cqA * 10];
        awA[0] = pack2h(accA[0], accA[1]);
        awA[1] = pack2h(accA[2], accA[3]);
        awA[2] = pack2h(accA[4], accA[5]);
        awA[3] = pack2h(accA[6], accA[7]);
        awA[4] = pack2h(accA[8], accA[9]);
        A_s[wid * APAD + 800 + cqA] = f2h_u(xin[(size_t)n * CQ + cqA]);
        if (g != 0) {
            unsigned* awB = (unsigned*)&A_s[wid * APAD + cqB * 10];
            awB[0] = pack2h(accB[0], accB[1]);
            awB[1] = pack2h(accB[2], accB[3]);
            awB[2] = pack2h(accB[4], accB[5]);
            awB[3] = pack2h(accB[6], accB[7]);
            awB[4] = pack2h(accB[8], accB[9]);
            A_s[wid * APAD + 800 + cqB] = f2h_u(xin[(size_t)n * CQ + cqB]);
        }
    }
    if (lane < 16) A_s[wid * APAD + 880 + lane] = 0;

    __syncthreads();

    // ---- GEMM: y[8 x 80] = A_s[8 x 896] @ B'[896 x 80] (waves 0-4) ----
    // A row = lrow&7 (rows 8-15 duplicate rows 0-7; D rows 8-15 discarded).
    if (tid < 320) {
        const int nt = tid >> 6, lq = tid & 63;
        const int lrow = lq & 15, quad = lq >> 4;
        const int arow = lrow & 7;
        const f16x8* __restrict__ wf = (const f16x8*)Wt;
        f32x4 acc = (f32x4){0.f, 0.f, 0.f, 0.f};
        #pragma unroll 4
        for (int ks = 0; ks < KS; ++ks) {
            f16x8 bfrag = wf[(ks * 5 + nt) * 64 + lq];
            f16x8 a = *(const f16x8*)(&A_s[arow * APAD + 32 * ks + 8 * quad]);
            acc = __builtin_amdgcn_mfma_f32_16x16x32_f16(a, bfrag, acc, 0, 0, 0);
        }
        const int op = 16 * nt + lrow;
        const float bias = (op % 5 == 0) ? b[op / 5] : 0.0f;
        if (quad < 2) {                          // D rows 0..7 only
            #pragma unroll
            for (int r = 0; r < 4; ++r)
                y_s[(quad * 4 + r) * OP + op] = acc[r] + bias;
        }
    }
    __syncthreads();

    // ---- epilogue: 128 threads, one (node, channel) each ----
    if (tid < 128) {
        const int nl = tid >> 4;                 // node 0..7
        const int ch = tid & 15;                 // channel
        const float* vp = &y_s[nl * OP + ch * 5];
        float a0 = vp[0], a1 = vp[1], a2 = vp[2], a3 = vp[3], a4 = vp[4];
        if (res != nullptr) {
            const float* rp = res + (size_t)(n0 + nl) * CQ + ch * 5;
            a0 += rp[0]; a1 += rp[1]; a2 += rp[2]; a3 += rp[3]; a4 += rp[4];
        }
        float o0 = 0.f, o1 = 0.f, o2 = 0.f, o3 = 0.f, o4 = 0.f;
        #pragma unroll
        for (int k = 0; k < 7; ++k) {
            float th = (float)(2.0 * M_PI / 7.0) * (float)k;
            float c1k = cosf(th), s1k = sinf(th);
            float c2k = cosf(2.0f * th), s2k = sinf(2.0f * th);
            float s = a0 + a1 * c1k + a2 * s1k + a3 * c2k + a4 * s2k;
            s = fmaxf(s, 0.0f);
            o0 += s;
            o1 += s * c1k; o2 += s * s1k;
            o3 += s * c2k; o4 += s * s2k;
        }
        const float i7 = 1.0f / 7.0f, t7 = 2.0f / 7.0f;
        float* po = outp + (size_t)(n0 + nl) * OP + ch * 5;
        po[0] = o0 * i7;
        po[1] = o1 * t7; po[2] = o2 * t7;
        po[3] = o3 * t7; po[4] = o4 * t7;
    }
}

// ---------------------------------------------------------------------------
extern "C" void kernel_launch(void* const* d_in, const int* in_sizes, int n_in,
                              void* d_out, int out_size, void* d_ws, size_t ws_size,
                              hipStream_t stream) {
    const float* x    = (const float*)d_in[0];
    const int*   ei   = (const int*)d_in[1];      // int inputs arrive as int32
    const float* pre  = (const float*)d_in[2];
    const float* phi  = (const float*)d_in[3];
    const float* W1   = (const float*)d_in[4];
    const float* b1   = (const float*)d_in[5];
    const float* Ws1  = (const float*)d_in[6];
    const float* W2   = (const float*)d_in[7];
    const float* b2   = (const float*)d_in[8];
    const float* Ws2  = (const float*)d_in[9];
    float* out = (float*)d_out;

    // Workspace layout (~37 MB of the 256 MB ws)
    unsigned short* Wt1 = (unsigned short*)d_ws;            // 143.4 KB
    unsigned short* Wt2 = Wt1 + WTN;                        // 143.4 KB
    float* h  = (float*)(Wt2 + WTN);                        // 3.2 MB
    float4* recs = (float4*)(h + (size_t)NN * OP);          // 30.72 MB (16B aligned)
    int* srcs   = (int*)(recs + (size_t)NN * MAXDEG * 3);   // 2.56 MB
    int* cnt    = srcs + (size_t)NN * MAXDEG;               // 40 KB

    // 4-dispatch chain: memset -> prep_all -> layer1 -> layer2
    hipMemsetAsync(cnt, 0, NN * sizeof(int), stream);
    prep_all<<<(NE + 255) / 256, 256, 0, stream>>>(ei, phi, pre, W1, Ws1, W2, Ws2,
                                                   cnt, srcs, recs, Wt1, Wt2);
    layer_fused<<<NN / NPB, 512, 0, stream>>>(x, srcs, recs, cnt, Wt1, b1, nullptr, h);
    layer_fused<<<NN / NPB, 512, 0, stream>>>(h, srcs, recs, cnt, Wt2, b2, x, out);
}